// Round 9
// baseline (40.909 us; speedup 1.0000x reference)
//
#include <hip/hip_runtime.h>
#include <math.h>

#define DIM   100
#define NV    64
#define BS    512
#define MAXCH 1664   // 128 combos * 13 chunks max, multiple of 128
#define PXW   104    // px row stride (u16 units), 8B-aligned rows
#define SHWC  (0.5f / 255.0f)

// ---------------------------------------------------------------------------
// One block per (batch, direction m). Bilinear mask staged as PACKED X-PAIRS:
// px[y][i] = (m[y][i] | m[y][min(i+1,99)]<<8) u8x2 in u16; slot i=100 holds
// (m[y][0], m[y][0]) for the ix0==-1 clamp case -> one ds_read_u16 per row
// gives both x-texels, EXACTLY matching the ref's clamped gather. Per combo:
// binary-search exact last valid step T (bit-exact float exprs), K = cells
// crossed; kept samples enumerated directly (t = ceil((k+D)*B - 5e-3), B =
// rcp(|vu|) in-loop, one-step fixup vs bit-exact floor(u(t))). prm split:
// b128 {x0,y0,vx,vy} + b32 meta = sign*(K+0.5). LDS instr/sample: 1 tab/64 +
// b128 + b32 + 2 gathers ~= 4 (was 6). LDS ~26.7 KB -> 6 blocks/CU; each CU
// processes its 8 blocks without idling (LDS-throughput regime).
// ---------------------------------------------------------------------------
template<bool AX>
__device__ __forceinline__ float mainloop(
    const unsigned short* px, const float4* prmA, const float* meta,
    const unsigned short* chunkTab, int totE, int tid) {
  const int grp = tid >> 5;                // 0..7
  const int sub = (tid >> 3) & 3;          // 0..3
  const int st  = tid & 7;                 // kept-sample index within chunk
  const int base0 = grp * 16 + sub * 4;
  float acc = 0.0f;

  for (int i = 0; i * 128 < totE; ++i) {
    const ushort4 ent = *reinterpret_cast<const ushort4*>(
        &chunkTab[i * 128 + base0]);       // one ds_read_b64 per 256 samples

    #define SAMPLE(e) {                                                    \
      const int c = (e) >> 4;                                              \
      const float kf = (float)((((e) & 15) << 3) | st);                    \
      const float4 p = prmA[c];            /* ds_read_b128 */              \
      const float mt = meta[c];            /* ds_read_b32  */              \
      const float vu = AX ? p.z : p.w;                                     \
      const float u0 = AX ? p.x : p.y;                                     \
      const float fu0 = floorf(u0);                                        \
      const float Bv = __builtin_amdgcn_rcpf(fabsf(vu));                   \
      const float D  = (vu > 0.0f) ? (fu0 - u0) : (u0 - fu0 - 1.0f);       \
      const float te = ceilf((kf + D) * Bv - 0.005f);                      \
      const float ck = fu0 + ((vu > 0.0f) ? kf : -kf);                     \
      const float u1 = __fadd_rn(__fmul_rn(te, vu), u0);                   \
      float t = (floorf(u1) == ck) ? te : (te + 1.0f);                     \
      t = fminf(fmaxf(t, 0.0f), 300.0f);                                   \
      const float xs = __fadd_rn(__fmul_rn(t, p.z), p.x);                  \
      const float ys = __fadd_rn(__fmul_rn(t, p.w), p.y);                  \
      const float X0 = floorf(xs), Y0 = floorf(ys);                        \
      const float wx1 = xs - X0, wy1 = ys - Y0;                            \
      const float wx0 = 1.0f - wx1, wy0 = 1.0f - wy1;                      \
      const int ix0 = (int)X0, iy0 = (int)Y0;                              \
      const int ic  = min(max(ix0, -1), DIM - 1);                          \
      const int ip  = (ic < 0) ? 100 : ic;                                 \
      const int yi0 = min(max(iy0, 0), DIM - 1);                           \
      const int yi1 = min(max(iy0 + 1, 0), DIM - 1);                       \
      const unsigned int r0 = px[yi0 * PXW + ip];                          \
      const unsigned int r1 = px[yi1 * PXW + ip];                          \
      const float g00 = (float)(r0 & 255u), g10 = (float)(r0 >> 8);        \
      const float g01 = (float)(r1 & 255u), g11 = (float)(r1 >> 8);        \
      const float val = wy0 * (wx0 * g00 + wx1 * g10) +                    \
                        wy1 * (wx0 * g01 + wx1 * g11);                     \
      const float w = (kf < fabsf(mt)) ? __builtin_copysignf(SHWC, mt)     \
                                       : 0.0f;                             \
      acc = fmaf(w, val, acc);                                             \
    }
    SAMPLE(ent.x); SAMPLE(ent.y); SAMPLE(ent.z); SAMPLE(ent.w);
    #undef SAMPLE
  }
  return acc;
}

__global__ __launch_bounds__(256, 6) void diffiou_intersect(
    const float* __restrict__ poly, const float* __restrict__ gt_mask,
    float* __restrict__ ws) {
  __shared__ unsigned short px[DIM * PXW];       // 20800 B
  __shared__ float4 prmA[128];                   // 2048 B: x0,y0,vx,vy
  __shared__ float  meta[128];                   // 512 B: sign*(K+0.5)
  __shared__ unsigned short chunkTab[MAXCH];     // 3328 B
  __shared__ int   wsum[2];
  __shared__ int   totalChunks;
  __shared__ float red[4];

  const int bid = blockIdx.x;
  const int b   = bid >> 2;
  const int m   = bid & 3;
  const bool ax = (m < 2);                 // DIRECTIONS = x,x,y,y
  const int tid = threadIdx.x;

  // ---- phase 1: stage packed-pair mask (fp32 -> u8 pairs) ----
  {
    const float* src = gt_mask + (size_t)(b * 4 + m) * (DIM * DIM);
    for (int j = tid; j < 2500; j += 256) {
      const int y = j / 25;
      const int g = j - y * 25;
      const float4 v = *reinterpret_cast<const float4*>(&src[y * DIM + 4 * g]);
      const float v4 = src[y * DIM + min(4 * g + 4, DIM - 1)];
      const int c0 = __float2int_rn(v.x * 255.0f);
      const int c1 = __float2int_rn(v.y * 255.0f);
      const int c2 = __float2int_rn(v.z * 255.0f);
      const int c3 = __float2int_rn(v.w * 255.0f);
      const int c4 = __float2int_rn(v4  * 255.0f);
      ushort4 o;
      o.x = (unsigned short)(c0 | (c1 << 8));
      o.y = (unsigned short)(c1 | (c2 << 8));
      o.z = (unsigned short)(c2 | (c3 << 8));
      o.w = (unsigned short)(c3 | (c4 << 8));
      *reinterpret_cast<ushort4*>(&px[y * PXW + 4 * g]) = o;  // 8B-aligned
    }
    if (tid < DIM) {       // slot 100: (m[y][0], m[y][0]) for ix0 == -1
      const int c0 = __float2int_rn(src[tid * DIM] * 255.0f);
      px[tid * PXW + 100] = (unsigned short)(c0 | (c0 << 8));
    }
    for (int j = tid; j < MAXCH; j += 256) chunkTab[j] = 15;  // sentinel
  }

  // ---- per-combo setup ----
  int ncv = 0;
  if (tid < 128) {
    const int e  = tid >> 1;
    const int fb = tid & 1;
    const float* pb = poly + (size_t)b * NV * 2;
    const float ex0 = pb[e * 2 + 0], ey0 = pb[e * 2 + 1];
    const int   en  = (e + 1) & (NV - 1);
    const float ex1 = pb[en * 2 + 0], ey1 = pb[en * 2 + 1];
    const float sign = (ax ? (ex1 > ex0) : (ey1 > ey0)) ? 1.0f : -1.0f;
    const float x0 = fb ? ex1 : ex0, y0 = fb ? ey1 : ey0;
    const float x1 = fb ? ex0 : ex1, y1 = fb ? ey0 : ey1;
    float vx = (x1 - x0) + 1e-6f;
    float vy = (y1 - y0) + 1e-6f;
    const float n = __fsqrt_rn(__fadd_rn(__fmul_rn(vx, vx), __fmul_rn(vy, vy)));
    vx = __fdiv_rn(vx, n);
    vy = __fdiv_rn(vy, n);
    // bbox + tolerances; u-bound [0,99] folded into the axis coord (exact)
    float xlo = fminf(x0, x1) - 0.001f, xhi = fmaxf(x0, x1) + 0.001f;
    float ylo = fminf(y0, y1) - 0.001f, yhi = fmaxf(y0, y1) + 0.001f;
    if (ax) { xlo = fmaxf(xlo, 0.0f); xhi = fminf(xhi, (float)(DIM - 1)); }
    else    { ylo = fmaxf(ylo, 0.0f); yhi = fminf(yhi, (float)(DIM - 1)); }

    #define VALID_AT(tt, out) {                                   \
      const float tf_ = (float)(tt);                              \
      const float xs_ = __fadd_rn(__fmul_rn(tf_, vx), x0);        \
      const float ys_ = __fadd_rn(__fmul_rn(tf_, vy), y0);        \
      out = (xs_ <= xhi) && (xs_ >= xlo) &&                       \
            (ys_ <= yhi) && (ys_ >= ylo);                         \
    }
    int T;
    bool v200; VALID_AT(200, v200);
    if (v200) { T = 200; }
    else {
      int lo = 0, hi = 200;
      #pragma unroll
      for (int it = 0; it < 8; ++it) {
        const int mid = (lo + hi) >> 1;
        bool vm; VALID_AT(mid, vm);
        if (vm) lo = mid; else hi = mid;
      }
      T = lo;
    }
    #undef VALID_AT

    const float vu  = ax ? vx : vy;
    const float u0  = ax ? x0 : y0;
    const float fu0 = floorf(u0);
    const float uT  = __fadd_rn(__fmul_rn((float)T, vu), u0);
    int K = abs((int)floorf(uT) - (int)fu0);
    K = min(K, 99);
    prmA[tid] = make_float4(x0, y0, vx, vy);
    meta[tid] = sign * ((float)K + 0.5f);
    ncv = (K >> 3) + 1;                    // 8-kept chunks, <= 13
  }

  // ---- prefix scan (2 waves) + scatter chunk table ----
  int v = ncv;
  #pragma unroll
  for (int i = 1; i < 64; i <<= 1) {
    const int w = __shfl_up(v, i, 64);
    if ((tid & 63) >= i) v += w;
  }
  if (((tid & 63) == 63) && (tid < 128)) wsum[tid >> 6] = v;
  __syncthreads();
  if ((tid >= 64) && (tid < 128)) v += wsum[0];
  if (tid < 128) {
    const int start = v - ncv;
    for (int k = 0; k < ncv; ++k)
      chunkTab[start + k] = (unsigned short)((tid << 4) | k);
    if (tid == 127) totalChunks = v;
  }
  __syncthreads();

  const int totE = totalChunks;
  const float acc = ax ? mainloop<true >(px, prmA, meta, chunkTab, totE, tid)
                       : mainloop<false>(px, prmA, meta, chunkTab, totE, tid);

  // ---- block reduce (4 waves) ----
  float a = acc;
  #pragma unroll
  for (int o = 32; o > 0; o >>= 1) a += __shfl_xor(a, o, 64);
  if ((tid & 63) == 0) red[tid >> 6] = a;
  __syncthreads();
  if (tid == 0) {
    const float s = red[0] + red[1] + red[2] + red[3];
    ws[bid] = fabsf(s);
  }
}

// ---------------------------------------------------------------------------
// Kernel 2: per-batch areas + final IoU. One wave per batch.
// ---------------------------------------------------------------------------
__device__ __forceinline__ float wave_area(const float* P, int b, int v) {
  const float x0 = P[(size_t)(b * NV + v) * 2 + 0];
  const float y0 = P[(size_t)(b * NV + v) * 2 + 1];
  const int vn = (v + 1) & (NV - 1);
  const float x1 = P[(size_t)(b * NV + vn) * 2 + 0];
  const float y1 = P[(size_t)(b * NV + vn) * 2 + 1];
  float ym = y0;
  #pragma unroll
  for (int o = 32; o > 0; o >>= 1) ym = fmaxf(ym, __shfl_xor(ym, o, 64));
  float term = (x1 - x0) * (ym - (y1 + y0) * 0.5f);
  #pragma unroll
  for (int o = 32; o > 0; o >>= 1) term += __shfl_xor(term, o, 64);
  return fabsf(term);
}

__global__ __launch_bounds__(64) void diffiou_finalize(
    const float* __restrict__ poly, const float* __restrict__ gt,
    const float* __restrict__ ws, float* __restrict__ out) {
  const int b = blockIdx.x;
  const int v = threadIdx.x;
  const float pa = wave_area(poly, b, v);
  const float ga = wave_area(gt, b, v);
  if (v == 0) {
    const float ia = 0.25f * (ws[b * 4 + 0] + ws[b * 4 + 1] +
                              ws[b * 4 + 2] + ws[b * 4 + 3]);
    out[b] = ia / (pa + ga - ia);
  }
}

// ---------------------------------------------------------------------------
extern "C" void kernel_launch(void* const* d_in, const int* in_sizes, int n_in,
                              void* d_out, int out_size, void* d_ws, size_t ws_size,
                              hipStream_t stream) {
  const float* poly    = (const float*)d_in[0];
  const float* gt      = (const float*)d_in[1];
  const float* gt_mask = (const float*)d_in[2];
  float* out = (float*)d_out;
  float* ws  = (float*)d_ws;   // 2048 floats: |s| per (batch, direction)

  hipLaunchKernelGGL(diffiou_intersect, dim3(BS * 4), dim3(256), 0, stream,
                     poly, gt_mask, ws);
  hipLaunchKernelGGL(diffiou_finalize, dim3(BS), dim3(64), 0, stream,
                     poly, gt, ws, out);
}

// Round 10
// 33.651 us; speedup vs baseline: 1.2157x; 1.2157x over previous
//
#include <hip/hip_runtime.h>
#include <math.h>

#define DIM   100
#define NV    64
#define BS    512
#define MAXCH 1664          // 128 combos * 13 chunks max, multiple of 128
#define SMW   108           // padded mask row stride (bytes)
#define SMH   103           // padded mask rows

// ---------------------------------------------------------------------------
// One block per (batch, direction m). Mask staged as u8 in a CLAMP-PADDED
// 103x108 layout: row r = m[clamp(r-1,0,99)], col 3 = m[.][0], cols 4..103 =
// m[.][0..99], cols 104,105 = m[.][99]. Gather for corner (ix0,iy0) (ix0,iy0
// in [-1,100] incl. overshoot) is then 4 ds_read_u8 at base+{112,113,220,221}
// with base = iy*108 + ix and iy=clamp((int)Y0,-1,100) etc. — reproduces the
// ref's clip() EXACTLY with ~11 fewer VALU ops/sample. Kept-sample direct
// enumeration as R7/R8: t = ceil(fmaf(kf,B,A')) (A' = D*B - 0.005 at setup),
// one-step fixup vs bit-exact floor(u(t)), t = max(t,0). 8-kept chunks,
// strided pool, ds_read_b64 entry quad (ILP x4). LDS ~18.8 KB -> 8 blocks/CU,
// 2048-block grid fully co-resident (R9 lesson: never drop below this).
// ---------------------------------------------------------------------------
template<bool AX>
__device__ __forceinline__ float mainloop(
    const unsigned char* sm, const float4* prmA, const float4* prmB,
    const unsigned short* chunkTab, int totE, int tid) {
  const int grp = tid >> 5;                // 0..7
  const int sub = (tid >> 3) & 3;          // 0..3
  const int st  = tid & 7;                 // kept-sample index within chunk
  const int base0 = grp * 16 + sub * 4;
  float acc = 0.0f;

  for (int i = 0; i * 128 < totE; ++i) {
    const ushort4 ent = *reinterpret_cast<const ushort4*>(
        &chunkTab[i * 128 + base0]);       // one ds_read_b64 per 256 samples

    // p = {x0,y0,vx,vy}; q = {shw, Kf, B, A'}
    #define SAMPLE(e) {                                                    \
      const int c = (e) >> 4;                                              \
      const float kf = (float)((((e) & 15) << 3) | st);                    \
      const float4 p = prmA[c];                                            \
      const float4 q = prmB[c];                                            \
      const float vu = AX ? p.z : p.w;                                     \
      const float u0 = AX ? p.x : p.y;                                     \
      const float fu0 = floorf(u0);                                        \
      const float ck = fu0 + __builtin_copysignf(kf, vu);                  \
      const float te = ceilf(fmaf(kf, q.z, q.w));                          \
      const float u1 = __fadd_rn(__fmul_rn(te, vu), u0);                   \
      float t = (floorf(u1) == ck) ? te : (te + 1.0f);                     \
      t = fmaxf(t, 0.0f);                                                  \
      const float xs = __fadd_rn(__fmul_rn(t, p.z), p.x);                  \
      const float ys = __fadd_rn(__fmul_rn(t, p.w), p.y);                  \
      const float X0 = floorf(xs), Y0 = floorf(ys);                        \
      const float wx1 = xs - X0, wy1 = ys - Y0;                            \
      const float wx0 = 1.0f - wx1, wy0 = 1.0f - wy1;                      \
      const int ix = max(min((int)X0, 100), -1);                           \
      const int iy = max(min((int)Y0, 100), -1);                           \
      const int a = iy * SMW + ix;                                         \
      const float g00 = (float)sm[a + (SMW + 4)];                          \
      const float g10 = (float)sm[a + (SMW + 5)];                          \
      const float g01 = (float)sm[a + (2 * SMW + 4)];                      \
      const float g11 = (float)sm[a + (2 * SMW + 5)];                      \
      const float top = fmaf(wx1, g10, wx0 * g00);                         \
      const float bot = fmaf(wx1, g11, wx0 * g01);                         \
      const float val = fmaf(wy1, bot, wy0 * top);                         \
      const float w = (kf <= q.y) ? q.x : 0.0f;                            \
      acc = fmaf(w, val, acc);                                             \
    }
    SAMPLE(ent.x); SAMPLE(ent.y); SAMPLE(ent.z); SAMPLE(ent.w);
    #undef SAMPLE
  }
  return acc;
}

__global__ __launch_bounds__(256, 8) void diffiou_intersect(
    const float* __restrict__ poly, const float* __restrict__ gt_mask,
    float* __restrict__ ws) {
  __shared__ unsigned char sm[SMH * SMW];        // 11124 B, clamp-padded
  __shared__ float4 prmA[128];                   // 2048 B: x0,y0,vx,vy
  __shared__ float4 prmB[128];                   // 2048 B: shw,Kf,B,A'
  __shared__ unsigned short chunkTab[MAXCH];     // 3328 B
  __shared__ int   wsum[2];
  __shared__ int   totalChunks;
  __shared__ float red[4];

  const int bid = blockIdx.x;
  const int b   = bid >> 2;
  const int m   = bid & 3;
  const bool ax = (m < 2);                 // DIRECTIONS = x,x,y,y
  const int tid = threadIdx.x;

  // ---- phase 1: stage clamp-padded u8 mask ----
  {
    const float* src = gt_mask + (size_t)(b * 4 + m) * (DIM * DIM);
    for (int j = tid; j < SMH * 25; j += 256) {
      const int r = j / 25;                // 0..102
      const int g = j - r * 25;            // 0..24
      const int sr = min(max(r - 1, 0), DIM - 1);
      const float4 v = *reinterpret_cast<const float4*>(&src[sr * DIM + 4 * g]);
      const unsigned int c0 = (unsigned int)__float2int_rn(v.x * 255.0f);
      const unsigned int c1 = (unsigned int)__float2int_rn(v.y * 255.0f);
      const unsigned int c2 = (unsigned int)__float2int_rn(v.z * 255.0f);
      const unsigned int c3 = (unsigned int)__float2int_rn(v.w * 255.0f);
      *reinterpret_cast<unsigned int*>(&sm[r * SMW + 4 + 4 * g]) =
          c0 | (c1 << 8) | (c2 << 16) | (c3 << 24);   // 4B-aligned
    }
    for (int r = tid; r < SMH; r += 256) { // border duplicates
      const int sr = min(max(r - 1, 0), DIM - 1);
      const unsigned char e0 =
          (unsigned char)__float2int_rn(src[sr * DIM + 0] * 255.0f);
      const unsigned char e9 =
          (unsigned char)__float2int_rn(src[sr * DIM + DIM - 1] * 255.0f);
      sm[r * SMW + 3] = e0;
      sm[r * SMW + 104] = e9;
      sm[r * SMW + 105] = e9;
    }
    for (int j = tid; j < MAXCH; j += 256) chunkTab[j] = 15;  // sentinel
  }

  // ---- per-combo setup ----
  int ncv = 0;
  if (tid < 128) {
    const int e  = tid >> 1;
    const int fb = tid & 1;
    const float* pb = poly + (size_t)b * NV * 2;
    const float ex0 = pb[e * 2 + 0], ey0 = pb[e * 2 + 1];
    const int   en  = (e + 1) & (NV - 1);
    const float ex1 = pb[en * 2 + 0], ey1 = pb[en * 2 + 1];
    const float sign = (ax ? (ex1 > ex0) : (ey1 > ey0)) ? 1.0f : -1.0f;
    const float x0 = fb ? ex1 : ex0, y0 = fb ? ey1 : ey0;
    const float x1 = fb ? ex0 : ex1, y1 = fb ? ey0 : ey1;
    float vx = (x1 - x0) + 1e-6f;
    float vy = (y1 - y0) + 1e-6f;
    const float n = __fsqrt_rn(__fadd_rn(__fmul_rn(vx, vx), __fmul_rn(vy, vy)));
    vx = __fdiv_rn(vx, n);
    vy = __fdiv_rn(vy, n);
    // bbox + tolerances; u-bound [0,99] folded into the axis coord (exact)
    float xlo = fminf(x0, x1) - 0.001f, xhi = fmaxf(x0, x1) + 0.001f;
    float ylo = fminf(y0, y1) - 0.001f, yhi = fmaxf(y0, y1) + 0.001f;
    if (ax) { xlo = fmaxf(xlo, 0.0f); xhi = fminf(xhi, (float)(DIM - 1)); }
    else    { ylo = fmaxf(ylo, 0.0f); yhi = fminf(yhi, (float)(DIM - 1)); }

    #define VALID_AT(tt, out) {                                   \
      const float tf_ = (float)(tt);                              \
      const float xs_ = __fadd_rn(__fmul_rn(tf_, vx), x0);        \
      const float ys_ = __fadd_rn(__fmul_rn(tf_, vy), y0);        \
      out = (xs_ <= xhi) && (xs_ >= xlo) &&                       \
            (ys_ <= yhi) && (ys_ >= ylo);                         \
    }
    int T;
    bool v200; VALID_AT(200, v200);
    if (v200) { T = 200; }
    else {
      int lo = 0, hi = 200;
      #pragma unroll
      for (int it = 0; it < 8; ++it) {
        const int mid = (lo + hi) >> 1;
        bool vm; VALID_AT(mid, vm);
        if (vm) lo = mid; else hi = mid;
      }
      T = lo;
    }
    #undef VALID_AT

    const float vu  = ax ? vx : vy;
    const float u0  = ax ? x0 : y0;
    const float fu0 = floorf(u0);
    const float uT  = __fadd_rn(__fmul_rn((float)T, vu), u0);
    int K = abs((int)floorf(uT) - (int)fu0);
    K = min(K, 99);
    const float B = __fdiv_rn(1.0f, fabsf(vu));
    const float D = (vu > 0.0f) ? (fu0 - u0) : (u0 - fu0 - 1.0f);
    prmA[tid] = make_float4(x0, y0, vx, vy);
    prmB[tid] = make_float4(sign * (0.5f / 255.0f), (float)K,
                            B, fmaf(D, B, -0.005f));
    ncv = (K >> 3) + 1;                    // 8-kept chunks, <= 13
  }

  // ---- prefix scan (2 waves) + scatter chunk table ----
  int v = ncv;
  #pragma unroll
  for (int i = 1; i < 64; i <<= 1) {
    const int w = __shfl_up(v, i, 64);
    if ((tid & 63) >= i) v += w;
  }
  if (((tid & 63) == 63) && (tid < 128)) wsum[tid >> 6] = v;
  __syncthreads();
  if ((tid >= 64) && (tid < 128)) v += wsum[0];
  if (tid < 128) {
    const int start = v - ncv;
    for (int k = 0; k < ncv; ++k)
      chunkTab[start + k] = (unsigned short)((tid << 4) | k);
    if (tid == 127) totalChunks = v;
  }
  __syncthreads();

  const int totE = totalChunks;
  const float acc = ax ? mainloop<true >(sm, prmA, prmB, chunkTab, totE, tid)
                       : mainloop<false>(sm, prmA, prmB, chunkTab, totE, tid);

  // ---- block reduce (4 waves) ----
  float a = acc;
  #pragma unroll
  for (int o = 32; o > 0; o >>= 1) a += __shfl_xor(a, o, 64);
  if ((tid & 63) == 0) red[tid >> 6] = a;
  __syncthreads();
  if (tid == 0) {
    const float s = red[0] + red[1] + red[2] + red[3];
    ws[bid] = fabsf(s);
  }
}

// ---------------------------------------------------------------------------
// Kernel 2: per-batch areas + final IoU. One wave per batch.
// ---------------------------------------------------------------------------
__device__ __forceinline__ float wave_area(const float* P, int b, int v) {
  const float x0 = P[(size_t)(b * NV + v) * 2 + 0];
  const float y0 = P[(size_t)(b * NV + v) * 2 + 1];
  const int vn = (v + 1) & (NV - 1);
  const float x1 = P[(size_t)(b * NV + vn) * 2 + 0];
  const float y1 = P[(size_t)(b * NV + vn) * 2 + 1];
  float ym = y0;
  #pragma unroll
  for (int o = 32; o > 0; o >>= 1) ym = fmaxf(ym, __shfl_xor(ym, o, 64));
  float term = (x1 - x0) * (ym - (y1 + y0) * 0.5f);
  #pragma unroll
  for (int o = 32; o > 0; o >>= 1) term += __shfl_xor(term, o, 64);
  return fabsf(term);
}

__global__ __launch_bounds__(64) void diffiou_finalize(
    const float* __restrict__ poly, const float* __restrict__ gt,
    const float* __restrict__ ws, float* __restrict__ out) {
  const int b = blockIdx.x;
  const int v = threadIdx.x;
  const float pa = wave_area(poly, b, v);
  const float ga = wave_area(gt, b, v);
  if (v == 0) {
    const float ia = 0.25f * (ws[b * 4 + 0] + ws[b * 4 + 1] +
                              ws[b * 4 + 2] + ws[b * 4 + 3]);
    out[b] = ia / (pa + ga - ia);
  }
}

// ---------------------------------------------------------------------------
extern "C" void kernel_launch(void* const* d_in, const int* in_sizes, int n_in,
                              void* d_out, int out_size, void* d_ws, size_t ws_size,
                              hipStream_t stream) {
  const float* poly    = (const float*)d_in[0];
  const float* gt      = (const float*)d_in[1];
  const float* gt_mask = (const float*)d_in[2];
  float* out = (float*)d_out;
  float* ws  = (float*)d_ws;   // 2048 floats: |s| per (batch, direction)

  hipLaunchKernelGGL(diffiou_intersect, dim3(BS * 4), dim3(256), 0, stream,
                     poly, gt_mask, ws);
  hipLaunchKernelGGL(diffiou_finalize, dim3(BS), dim3(64), 0, stream,
                     poly, gt, ws, out);
}